// Round 2
// baseline (417.837 us; speedup 1.0000x reference)
//
#include <hip/hip_runtime.h>

// SparseVoxelEncoder: trilinear interpolation of 8 corner embeddings per point.
// out[p, :] = sum_{c=0}^{7} w_c(p) * values[point_feats[sampled_idx[p]][c], :]
//
// R5: voxel-grouped two-phase execution.
// Evidence: values gather is 8M x 128B = 1.024 GB logical over a 76.8 MB table;
// measured hit rate ~41% == aggregate-L2 (32MB) / footprint (77MB) -> Infinity
// Cache contributes ~nothing for this random pattern, and R2-R4 proved cache-
// policy hints (nt / nt sc0 sc1) don't change FETCH_SIZE at all.
// Fix at the source: counting-sort points by voxel (P=2H -> ~2 pts/voxel), then
// one 8-lane group per voxel loads the 8 corner rows ONCE into registers and
// applies them to all its points. Values logical traffic 8M -> 3.63M rows.
// point_xyz / point_feats reads become sequential streams as a bonus.
//
// Pipeline (all on `stream`, graph-capture safe; no hipMalloc/hipMemcpy):
//   memset counts -> k_hist -> k_scan_a/b/c (2-level exclusive scan)
//   -> k_scatter (perm) -> svenc_voxel (main)
// Falls back to the R1 direct kernel if workspace is too small.
//
// Layout in main kernel: 8 lanes per voxel; lane `sub` owns float4 chunk
// d[4*sub..4*sub+3]. Corner order matches jax meshgrid 'ij':
// c bits = (x=c>>2, y=(c>>1)&1, z=c&1). Per-point arithmetic identical to the
// direct kernel -> bit-identical output (absmax must stay 0).

#define VOXEL_INV 4.0f  // 1 / 0.25

typedef float vfloat4 __attribute__((ext_vector_type(4)));

// ---------------------------------------------------------------- direct path
__global__ __launch_bounds__(256) void svenc_direct(
    const float* __restrict__ sampled_xyz,
    const float* __restrict__ point_xyz,
    const float* __restrict__ values,
    const int*   __restrict__ sampled_idx,
    const int*   __restrict__ point_feats,
    float*       __restrict__ out,
    int P)
{
    int t   = blockIdx.x * blockDim.x + threadIdx.x;
    int pid = t >> 3;
    int sub = t & 7;
    if (pid >= P) return;

    int vi = __builtin_nontemporal_load(sampled_idx + pid);

    float sx = __builtin_nontemporal_load(sampled_xyz + pid * 3 + 0);
    float sy = __builtin_nontemporal_load(sampled_xyz + pid * 3 + 1);
    float sz = __builtin_nontemporal_load(sampled_xyz + pid * 3 + 2);

    float cx = point_xyz[(size_t)vi * 3 + 0];
    float cy = point_xyz[(size_t)vi * 3 + 1];
    float cz = point_xyz[(size_t)vi * 3 + 2];

    float px = (sx - cx) * VOXEL_INV + 0.5f;
    float py = (sy - cy) * VOXEL_INV + 0.5f;
    float pz = (sz - cz) * VOXEL_INV + 0.5f;

    float xs[2] = {1.0f - px, px};
    float ys[2] = {1.0f - py, py};
    float zs[2] = {1.0f - pz, pz};

    const int4* pf4 = (const int4*)(point_feats + ((size_t)vi << 3));
    int4 f0 = pf4[0];
    int4 f1 = pf4[1];
    int ids[8] = {f0.x, f0.y, f0.z, f0.w, f1.x, f1.y, f1.z, f1.w};

    vfloat4 acc = {0.0f, 0.0f, 0.0f, 0.0f};
#pragma unroll
    for (int c = 0; c < 8; ++c) {
        float w = xs[(c >> 2) & 1] * ys[(c >> 1) & 1] * zs[c & 1];
        const vfloat4 v = ((const vfloat4*)(values + ((size_t)ids[c] << 5)))[sub];
        acc += w * v;
    }
    __builtin_nontemporal_store(acc, (vfloat4*)(out + ((size_t)pid << 5)) + sub);
}

// ---------------------------------------------------------------- sort passes
__global__ __launch_bounds__(256) void k_hist(
    const int* __restrict__ idx, int* __restrict__ counts, int P)
{
    int p = blockIdx.x * 256 + threadIdx.x;
    if (p < P) atomicAdd(&counts[idx[p]], 1);
}

// per-block (2048 counts) reduction -> blockSums[b]
__global__ __launch_bounds__(256) void k_scan_a(
    const int* __restrict__ counts, int* __restrict__ blockSums, int H)
{
    __shared__ int s[256];
    int b = blockIdx.x, tid = threadIdx.x;
    int base = b * 2048 + tid * 8;
    int sum = 0;
    if (base + 8 <= H) {
        const int4* c4 = (const int4*)(counts + base);
        int4 a = c4[0], bb = c4[1];
        sum = a.x + a.y + a.z + a.w + bb.x + bb.y + bb.z + bb.w;
    } else {
        for (int j = 0; j < 8; ++j) if (base + j < H) sum += counts[base + j];
    }
    s[tid] = sum; __syncthreads();
    for (int off = 128; off > 0; off >>= 1) {
        if (tid < off) s[tid] += s[tid + off];
        __syncthreads();
    }
    if (tid == 0) blockSums[b] = s[0];
}

// single-block exclusive scan of nb (<=256) block sums -> blockBase
__global__ __launch_bounds__(256) void k_scan_b(
    const int* __restrict__ blockSums, int* __restrict__ blockBase, int nb)
{
    __shared__ int s[256];
    int tid = threadIdx.x;
    int v = (tid < nb) ? blockSums[tid] : 0;
    s[tid] = v; __syncthreads();
    for (int off = 1; off < 256; off <<= 1) {
        int t = (tid >= off) ? s[tid - off] : 0;
        __syncthreads();
        s[tid] += t;
        __syncthreads();
    }
    if (tid < nb) blockBase[tid] = s[tid] - v;   // exclusive
}

// per-block exclusive scan of its 2048 counts + blockBase -> offsets, cursor
__global__ __launch_bounds__(256) void k_scan_c(
    const int* __restrict__ counts, const int* __restrict__ blockBase,
    int* __restrict__ offsets, int* __restrict__ cursor, int H)
{
    __shared__ int s[256];
    int b = blockIdx.x, tid = threadIdx.x;
    int base = b * 2048 + tid * 8;
    int c[8]; int sum = 0;
#pragma unroll
    for (int j = 0; j < 8; ++j) {
        int h = base + j;
        c[j] = (h < H) ? counts[h] : 0;
        sum += c[j];
    }
    s[tid] = sum; __syncthreads();
    for (int off = 1; off < 256; off <<= 1) {
        int t = (tid >= off) ? s[tid - off] : 0;
        __syncthreads();
        s[tid] += t;
        __syncthreads();
    }
    int run = blockBase[b] + s[tid] - sum;   // exclusive prefix for this thread
#pragma unroll
    for (int j = 0; j < 8; ++j) {
        int h = base + j;
        if (h < H) { offsets[h] = run; cursor[h] = run; run += c[j]; }
    }
}

__global__ __launch_bounds__(256) void k_scatter(
    const int* __restrict__ idx, int* __restrict__ cursor,
    int* __restrict__ perm, int P)
{
    int p = blockIdx.x * 256 + threadIdx.x;
    if (p < P) {
        int pos = atomicAdd(&cursor[idx[p]], 1);
        perm[pos] = p;
    }
}

// ---------------------------------------------------------------- main kernel
__global__ __launch_bounds__(256) void svenc_voxel(
    const float* __restrict__ sampled_xyz,   // [P,3]
    const float* __restrict__ point_xyz,     // [H,3]
    const float* __restrict__ values,        // [NEMB,32]
    const int*   __restrict__ point_feats,   // [H,8]
    const int*   __restrict__ offsets,       // [H] segment starts
    const int*   __restrict__ counts,        // [H] segment lengths
    const int*   __restrict__ perm,          // [P] point ids grouped by voxel
    float*       __restrict__ out,           // [P,32]
    int H)
{
    int t   = blockIdx.x * 256 + threadIdx.x;
    int g   = t >> 3;       // voxel index (sequential -> streaming voxel tables)
    int sub = t & 7;        // float4 chunk of the 32-float row
    if (g >= H) return;

    int n = counts[g];
    if (n == 0) return;
    int start = offsets[g];

    // sequential, coalesced voxel-table reads
    float cx = point_xyz[(size_t)g * 3 + 0];
    float cy = point_xyz[(size_t)g * 3 + 1];
    float cz = point_xyz[(size_t)g * 3 + 2];

    const int4* pf4 = (const int4*)(point_feats + ((size_t)g << 3));
    int4 f0 = pf4[0];
    int4 f1 = pf4[1];
    int ids[8] = {f0.x, f0.y, f0.z, f0.w, f1.x, f1.y, f1.z, f1.w};

    // load the 8 corner rows ONCE into registers (the whole point of R5)
    vfloat4 v[8];
#pragma unroll
    for (int c = 0; c < 8; ++c)
        v[c] = ((const vfloat4*)(values + ((size_t)ids[c] << 5)))[sub];

    for (int i = 0; i < n; ++i) {
        int p = perm[start + i];             // uniform across the 8 lanes

        float sx = sampled_xyz[(size_t)p * 3 + 0];
        float sy = sampled_xyz[(size_t)p * 3 + 1];
        float sz = sampled_xyz[(size_t)p * 3 + 2];

        float px = (sx - cx) * VOXEL_INV + 0.5f;
        float py = (sy - cy) * VOXEL_INV + 0.5f;
        float pz = (sz - cz) * VOXEL_INV + 0.5f;

        float xs[2] = {1.0f - px, px};
        float ys[2] = {1.0f - py, py};
        float zs[2] = {1.0f - pz, pz};

        vfloat4 acc = {0.0f, 0.0f, 0.0f, 0.0f};
#pragma unroll
        for (int c = 0; c < 8; ++c) {
            float w = xs[(c >> 2) & 1] * ys[(c >> 1) & 1] * zs[c & 1];
            acc += w * v[c];
        }
        __builtin_nontemporal_store(acc, (vfloat4*)(out + ((size_t)p << 5)) + sub);
    }
}

// ---------------------------------------------------------------- launcher
extern "C" void kernel_launch(void* const* d_in, const int* in_sizes, int n_in,
                              void* d_out, int out_size, void* d_ws, size_t ws_size,
                              hipStream_t stream) {
    const float* sampled_xyz = (const float*)d_in[0];
    const float* point_xyz   = (const float*)d_in[1];
    const float* values      = (const float*)d_in[2];
    const int*   sampled_idx = (const int*)d_in[3];
    const int*   point_feats = (const int*)d_in[4];
    float* out = (float*)d_out;

    int P = in_sizes[3];   // element count of sampled_idx == number of points

    // H: handle both in_sizes conventions (total elements vs first-dim).
    // element-count: in_sizes[0] = 3P, in_sizes[4] = 8H.  first-dim: = P, = H.
    int H;
    if (in_sizes[0] == 3 * P)       H = in_sizes[4] / 8;
    else                            H = in_sizes[4];

    int nb = (H + 2047) / 2048;                      // scan blocks
    size_t need_ints = (size_t)3 * H + 512 + (size_t)P;
    bool sorted_ok = (d_ws != nullptr) && (ws_size >= need_ints * 4) &&
                     (H > 0) && (nb <= 256);

    if (!sorted_ok) {
        long total_threads = (long)P * 8;
        int grid = (int)((total_threads + 255) / 256);
        svenc_direct<<<grid, 256, 0, stream>>>(
            sampled_xyz, point_xyz, values, sampled_idx, point_feats, out, P);
        return;
    }

    int* ws        = (int*)d_ws;
    int* counts    = ws;                  // [H]
    int* blockSums = ws + H;              // [256]
    int* blockBase = ws + H + 256;        // [256]
    int* offsets   = ws + H + 512;        // [H]
    int* cursor    = ws + 2 * (size_t)H + 512;  // [H]
    int* perm      = ws + 3 * (size_t)H + 512;  // [P]

    hipMemsetAsync(counts, 0, (size_t)H * 4, stream);

    int gp = (P + 255) / 256;
    k_hist   <<<gp, 256, 0, stream>>>(sampled_idx, counts, P);
    k_scan_a <<<nb, 256, 0, stream>>>(counts, blockSums, H);
    k_scan_b <<<1,  256, 0, stream>>>(blockSums, blockBase, nb);
    k_scan_c <<<nb, 256, 0, stream>>>(counts, blockBase, offsets, cursor, H);
    k_scatter<<<gp, 256, 0, stream>>>(sampled_idx, cursor, perm, P);

    long tt = (long)H * 8;
    int grid = (int)((tt + 255) / 256);
    svenc_voxel<<<grid, 256, 0, stream>>>(
        sampled_xyz, point_xyz, values, point_feats,
        offsets, counts, perm, out, H);
}

// Round 3
// 371.280 us; speedup vs baseline: 1.1254x; 1.1254x over previous
//
#include <hip/hip_runtime.h>

// SparseVoxelEncoder: trilinear interpolation of 8 corner embeddings per point.
// out[p, :] = sum_{c=0}^{7} w_c(p) * values[point_feats[sampled_idx[p]][c], :]
//
// R6: fused bucket-scatter grouping (replaces R5's 6-dispatch counting sort).
// R5 post-mortem: voxel-grouping the main kernel works (FETCH 641->300 MB,
// 221->127 us) but the sort preamble cost ~135 us and regressed the bench.
// Fix: single fused pass  pos = atomicAdd(&counts[vi],1);
//                         bucket[vi*8+pos] = {bitcast(p), sx, sy, sz};
// - 2 aux dispatches instead of 6, one atomic pass instead of two, no scan.
// - bucket entry carries the point's xyz -> main kernel loses the scattered
//   sampled_xyz gather (~70 MB of line-granular fetch in R5).
// - counts ~ Poisson(2): P(n>8) ~ 2e-4/voxel -> ~1e2 overflow points total;
//   those are computed directly inside the bucket pass (same FLOP order ->
//   bit-identical output, absmax must stay 0).
// Workspace tiers: xyz-bucket (69.2 MB) > id-bucket (18.9 MB) > direct kernel.

#define VOXEL_INV 4.0f  // 1 / 0.25
#define CAP 8           // bucket slots per voxel

typedef float vfloat4 __attribute__((ext_vector_type(4)));

// ---- shared per-point math (identical FLOP order everywhere -> bit-identical)
__device__ __forceinline__ void corner_ids(const int* __restrict__ point_feats,
                                           int vi, int* ids)
{
    const int4* pf4 = (const int4*)(point_feats + ((size_t)vi << 3));
    int4 f0 = pf4[0];
    int4 f1 = pf4[1];
    ids[0] = f0.x; ids[1] = f0.y; ids[2] = f0.z; ids[3] = f0.w;
    ids[4] = f1.x; ids[5] = f1.y; ids[6] = f1.z; ids[7] = f1.w;
}

// full 32-float row for one point, single thread (rare overflow path)
__device__ void compute_point_direct(
    const float* __restrict__ point_xyz,
    const float* __restrict__ values,
    const int*   __restrict__ point_feats,
    float*       __restrict__ out,
    int vi, int p, float sx, float sy, float sz)
{
    float cx = point_xyz[(size_t)vi * 3 + 0];
    float cy = point_xyz[(size_t)vi * 3 + 1];
    float cz = point_xyz[(size_t)vi * 3 + 2];

    float px = (sx - cx) * VOXEL_INV + 0.5f;
    float py = (sy - cy) * VOXEL_INV + 0.5f;
    float pz = (sz - cz) * VOXEL_INV + 0.5f;

    float xs[2] = {1.0f - px, px};
    float ys[2] = {1.0f - py, py};
    float zs[2] = {1.0f - pz, pz};

    int ids[8];
    corner_ids(point_feats, vi, ids);

    vfloat4 acc[8] = {};
#pragma unroll
    for (int c = 0; c < 8; ++c) {
        float w = xs[(c >> 2) & 1] * ys[(c >> 1) & 1] * zs[c & 1];
        const vfloat4* vr = (const vfloat4*)(values + ((size_t)ids[c] << 5));
#pragma unroll
        for (int k = 0; k < 8; ++k) acc[k] += w * vr[k];
    }
    vfloat4* o = (vfloat4*)(out + ((size_t)p << 5));
#pragma unroll
    for (int k = 0; k < 8; ++k) __builtin_nontemporal_store(acc[k], o + k);
}

// ---------------------------------------------------------------- direct path
__global__ __launch_bounds__(256) void svenc_direct(
    const float* __restrict__ sampled_xyz,
    const float* __restrict__ point_xyz,
    const float* __restrict__ values,
    const int*   __restrict__ sampled_idx,
    const int*   __restrict__ point_feats,
    float*       __restrict__ out,
    int P)
{
    int t   = blockIdx.x * blockDim.x + threadIdx.x;
    int pid = t >> 3;
    int sub = t & 7;
    if (pid >= P) return;

    int vi = __builtin_nontemporal_load(sampled_idx + pid);
    float sx = __builtin_nontemporal_load(sampled_xyz + pid * 3 + 0);
    float sy = __builtin_nontemporal_load(sampled_xyz + pid * 3 + 1);
    float sz = __builtin_nontemporal_load(sampled_xyz + pid * 3 + 2);

    float cx = point_xyz[(size_t)vi * 3 + 0];
    float cy = point_xyz[(size_t)vi * 3 + 1];
    float cz = point_xyz[(size_t)vi * 3 + 2];

    float px = (sx - cx) * VOXEL_INV + 0.5f;
    float py = (sy - cy) * VOXEL_INV + 0.5f;
    float pz = (sz - cz) * VOXEL_INV + 0.5f;

    float xs[2] = {1.0f - px, px};
    float ys[2] = {1.0f - py, py};
    float zs[2] = {1.0f - pz, pz};

    int ids[8];
    corner_ids(point_feats, vi, ids);

    vfloat4 acc = {0.0f, 0.0f, 0.0f, 0.0f};
#pragma unroll
    for (int c = 0; c < 8; ++c) {
        float w = xs[(c >> 2) & 1] * ys[(c >> 1) & 1] * zs[c & 1];
        const vfloat4 v = ((const vfloat4*)(values + ((size_t)ids[c] << 5)))[sub];
        acc += w * v;
    }
    __builtin_nontemporal_store(acc, (vfloat4*)(out + ((size_t)pid << 5)) + sub);
}

// ------------------------------------------------------- tier 1: xyz buckets
__global__ __launch_bounds__(256) void k_bucket_xyz(
    const float* __restrict__ sampled_xyz,
    const float* __restrict__ point_xyz,
    const float* __restrict__ values,
    const int*   __restrict__ sampled_idx,
    const int*   __restrict__ point_feats,
    float*       __restrict__ out,
    int*         __restrict__ counts,
    vfloat4*     __restrict__ bucket,   // [H*CAP] {bitcast(p), sx, sy, sz}
    int P)
{
    int p = blockIdx.x * 256 + threadIdx.x;
    if (p >= P) return;

    int vi = sampled_idx[p];
    float sx = sampled_xyz[(size_t)p * 3 + 0];
    float sy = sampled_xyz[(size_t)p * 3 + 1];
    float sz = sampled_xyz[(size_t)p * 3 + 2];

    int pos = atomicAdd(counts + vi, 1);
    if (pos < CAP) {
        vfloat4 e;
        e.x = __int_as_float(p);
        e.y = sx; e.z = sy; e.w = sz;
        bucket[((size_t)vi << 3) + pos] = e;
    } else {
        // rare (~1e2 points total): compute in-place, fully correct
        compute_point_direct(point_xyz, values, point_feats, out, vi, p, sx, sy, sz);
    }
}

__global__ __launch_bounds__(256) void svenc_voxel_xyz(
    const float* __restrict__ point_xyz,
    const float* __restrict__ values,
    const int*   __restrict__ point_feats,
    const int*   __restrict__ counts,
    const vfloat4* __restrict__ bucket,
    float*       __restrict__ out,
    int H)
{
    int t   = blockIdx.x * 256 + threadIdx.x;
    int g   = t >> 3;       // voxel index (sequential -> streaming voxel tables)
    int sub = t & 7;        // float4 chunk of the 32-float row
    if (g >= H) return;

    int n = counts[g];
    if (n == 0) return;
    if (n > CAP) n = CAP;

    float cx = point_xyz[(size_t)g * 3 + 0];
    float cy = point_xyz[(size_t)g * 3 + 1];
    float cz = point_xyz[(size_t)g * 3 + 2];

    int ids[8];
    corner_ids(point_feats, g, ids);

    // 8 corner rows loaded ONCE into registers, reused for all points in voxel
    vfloat4 v[8];
#pragma unroll
    for (int c = 0; c < 8; ++c)
        v[c] = ((const vfloat4*)(values + ((size_t)ids[c] << 5)))[sub];

    for (int i = 0; i < n; ++i) {
        vfloat4 e = bucket[((size_t)g << 3) + i];   // broadcast across 8 lanes
        int p = __float_as_int(e.x);

        float px = (e.y - cx) * VOXEL_INV + 0.5f;
        float py = (e.z - cy) * VOXEL_INV + 0.5f;
        float pz = (e.w - cz) * VOXEL_INV + 0.5f;

        float xs[2] = {1.0f - px, px};
        float ys[2] = {1.0f - py, py};
        float zs[2] = {1.0f - pz, pz};

        vfloat4 acc = {0.0f, 0.0f, 0.0f, 0.0f};
#pragma unroll
        for (int c = 0; c < 8; ++c) {
            float w = xs[(c >> 2) & 1] * ys[(c >> 1) & 1] * zs[c & 1];
            acc += w * v[c];
        }
        __builtin_nontemporal_store(acc, (vfloat4*)(out + ((size_t)p << 5)) + sub);
    }
}

// -------------------------------------------------------- tier 2: id buckets
__global__ __launch_bounds__(256) void k_bucket_id(
    const float* __restrict__ sampled_xyz,
    const float* __restrict__ point_xyz,
    const float* __restrict__ values,
    const int*   __restrict__ sampled_idx,
    const int*   __restrict__ point_feats,
    float*       __restrict__ out,
    int*         __restrict__ counts,
    int*         __restrict__ bucket,   // [H*CAP] point ids
    int P)
{
    int p = blockIdx.x * 256 + threadIdx.x;
    if (p >= P) return;

    int vi = sampled_idx[p];
    int pos = atomicAdd(counts + vi, 1);
    if (pos < CAP) {
        bucket[((size_t)vi << 3) + pos] = p;
    } else {
        float sx = sampled_xyz[(size_t)p * 3 + 0];
        float sy = sampled_xyz[(size_t)p * 3 + 1];
        float sz = sampled_xyz[(size_t)p * 3 + 2];
        compute_point_direct(point_xyz, values, point_feats, out, vi, p, sx, sy, sz);
    }
}

__global__ __launch_bounds__(256) void svenc_voxel_id(
    const float* __restrict__ sampled_xyz,
    const float* __restrict__ point_xyz,
    const float* __restrict__ values,
    const int*   __restrict__ point_feats,
    const int*   __restrict__ counts,
    const int*   __restrict__ bucket,
    float*       __restrict__ out,
    int H)
{
    int t   = blockIdx.x * 256 + threadIdx.x;
    int g   = t >> 3;
    int sub = t & 7;
    if (g >= H) return;

    int n = counts[g];
    if (n == 0) return;
    if (n > CAP) n = CAP;

    float cx = point_xyz[(size_t)g * 3 + 0];
    float cy = point_xyz[(size_t)g * 3 + 1];
    float cz = point_xyz[(size_t)g * 3 + 2];

    int ids[8];
    corner_ids(point_feats, g, ids);

    vfloat4 v[8];
#pragma unroll
    for (int c = 0; c < 8; ++c)
        v[c] = ((const vfloat4*)(values + ((size_t)ids[c] << 5)))[sub];

    for (int i = 0; i < n; ++i) {
        int p = bucket[((size_t)g << 3) + i];

        float sx = sampled_xyz[(size_t)p * 3 + 0];
        float sy = sampled_xyz[(size_t)p * 3 + 1];
        float sz = sampled_xyz[(size_t)p * 3 + 2];

        float px = (sx - cx) * VOXEL_INV + 0.5f;
        float py = (sy - cy) * VOXEL_INV + 0.5f;
        float pz = (sz - cz) * VOXEL_INV + 0.5f;

        float xs[2] = {1.0f - px, px};
        float ys[2] = {1.0f - py, py};
        float zs[2] = {1.0f - pz, pz};

        vfloat4 acc = {0.0f, 0.0f, 0.0f, 0.0f};
#pragma unroll
        for (int c = 0; c < 8; ++c) {
            float w = xs[(c >> 2) & 1] * ys[(c >> 1) & 1] * zs[c & 1];
            acc += w * v[c];
        }
        __builtin_nontemporal_store(acc, (vfloat4*)(out + ((size_t)p << 5)) + sub);
    }
}

// ---------------------------------------------------------------- launcher
extern "C" void kernel_launch(void* const* d_in, const int* in_sizes, int n_in,
                              void* d_out, int out_size, void* d_ws, size_t ws_size,
                              hipStream_t stream) {
    const float* sampled_xyz = (const float*)d_in[0];
    const float* point_xyz   = (const float*)d_in[1];
    const float* values      = (const float*)d_in[2];
    const int*   sampled_idx = (const int*)d_in[3];
    const int*   point_feats = (const int*)d_in[4];
    float* out = (float*)d_out;

    int P = in_sizes[3];   // element count of sampled_idx == number of points

    // H: handle both in_sizes conventions (total elements vs first-dim).
    int H;
    if (in_sizes[0] == 3 * P)       H = in_sizes[4] / 8;
    else                            H = in_sizes[4];

    size_t bucketB_xyz = (size_t)H * CAP * 16;   // vfloat4 per slot
    size_t need_xyz    = bucketB_xyz + (size_t)H * 4;
    size_t bucketB_id  = (size_t)H * CAP * 4;
    size_t need_id     = bucketB_id + (size_t)H * 4;

    int gp = (P + 255) / 256;                    // one thread per point
    long tt = (long)H * 8;
    int gm = (int)((tt + 255) / 256);            // 8 lanes per voxel

    if (d_ws != nullptr && ws_size >= need_xyz && H > 0) {
        vfloat4* bucket = (vfloat4*)d_ws;
        int* counts = (int*)((char*)d_ws + bucketB_xyz);
        hipMemsetAsync(counts, 0, (size_t)H * 4, stream);
        k_bucket_xyz<<<gp, 256, 0, stream>>>(
            sampled_xyz, point_xyz, values, sampled_idx, point_feats,
            out, counts, bucket, P);
        svenc_voxel_xyz<<<gm, 256, 0, stream>>>(
            point_xyz, values, point_feats, counts, bucket, out, H);
    } else if (d_ws != nullptr && ws_size >= need_id && H > 0) {
        int* bucket = (int*)d_ws;
        int* counts = (int*)((char*)d_ws + bucketB_id);
        hipMemsetAsync(counts, 0, (size_t)H * 4, stream);
        k_bucket_id<<<gp, 256, 0, stream>>>(
            sampled_xyz, point_xyz, values, sampled_idx, point_feats,
            out, counts, bucket, P);
        svenc_voxel_id<<<gm, 256, 0, stream>>>(
            sampled_xyz, point_xyz, values, point_feats, counts, bucket, out, H);
    } else {
        long total_threads = (long)P * 8;
        int grid = (int)((total_threads + 255) / 256);
        svenc_direct<<<grid, 256, 0, stream>>>(
            sampled_xyz, point_xyz, values, sampled_idx, point_feats, out, P);
    }
}

// Round 4
// 362.480 us; speedup vs baseline: 1.1527x; 1.0243x over previous
//
#include <hip/hip_runtime.h>

// SparseVoxelEncoder: trilinear interpolation of 8 corner embeddings per point.
// out[p, :] = sum_{c=0}^{7} w_c(p) * values[point_feats[sampled_idx[p]][c], :]
//
// R7: attack the bucket-scatter cost (~90 us for a pass that logically moves
// ~35 MB). Theory: 1M scattered 16-B stores into a 67 MB bucket region
// write-allocate (fetch 128-B line + writeback) -> 100-200 MB hidden traffic.
// R2-R4's null nt results were on FULL-line coalesced out stores (allocation
// irrelevant); partial-line scattered stores are where nt should matter.
// Changes vs R6:
//   - bucket-entry scatter uses __builtin_nontemporal_store (no-allocate hint)
//   - atomicAdd issued before the xyz loads (independent -> overlap latency)
//   - main kernel reads bucket/counts via nontemporal loads (read-once; don't
//     evict `values` from L2). Main is otherwise untouched -> its counters
//     (dur ~125 us, FETCH ~258 MB) act as the in-bench control.
// Main kernel is near its random-line pattern ceiling (389 MB @ 3.1 TB/s);
// corner ids are i.i.d. random -> no id-locality to exploit.

#define VOXEL_INV 4.0f  // 1 / 0.25
#define CAP 8           // bucket slots per voxel (128 B = one line per voxel)

typedef float vfloat4 __attribute__((ext_vector_type(4)));

// ---- shared per-point math (identical FLOP order everywhere -> bit-identical)
__device__ __forceinline__ void corner_ids(const int* __restrict__ point_feats,
                                           int vi, int* ids)
{
    const int4* pf4 = (const int4*)(point_feats + ((size_t)vi << 3));
    int4 f0 = pf4[0];
    int4 f1 = pf4[1];
    ids[0] = f0.x; ids[1] = f0.y; ids[2] = f0.z; ids[3] = f0.w;
    ids[4] = f1.x; ids[5] = f1.y; ids[6] = f1.z; ids[7] = f1.w;
}

// full 32-float row for one point, single thread (rare overflow path)
__device__ void compute_point_direct(
    const float* __restrict__ point_xyz,
    const float* __restrict__ values,
    const int*   __restrict__ point_feats,
    float*       __restrict__ out,
    int vi, int p, float sx, float sy, float sz)
{
    float cx = point_xyz[(size_t)vi * 3 + 0];
    float cy = point_xyz[(size_t)vi * 3 + 1];
    float cz = point_xyz[(size_t)vi * 3 + 2];

    float px = (sx - cx) * VOXEL_INV + 0.5f;
    float py = (sy - cy) * VOXEL_INV + 0.5f;
    float pz = (sz - cz) * VOXEL_INV + 0.5f;

    float xs[2] = {1.0f - px, px};
    float ys[2] = {1.0f - py, py};
    float zs[2] = {1.0f - pz, pz};

    int ids[8];
    corner_ids(point_feats, vi, ids);

    vfloat4 acc[8] = {};
#pragma unroll
    for (int c = 0; c < 8; ++c) {
        float w = xs[(c >> 2) & 1] * ys[(c >> 1) & 1] * zs[c & 1];
        const vfloat4* vr = (const vfloat4*)(values + ((size_t)ids[c] << 5));
#pragma unroll
        for (int k = 0; k < 8; ++k) acc[k] += w * vr[k];
    }
    vfloat4* o = (vfloat4*)(out + ((size_t)p << 5));
#pragma unroll
    for (int k = 0; k < 8; ++k) __builtin_nontemporal_store(acc[k], o + k);
}

// ---------------------------------------------------------------- direct path
__global__ __launch_bounds__(256) void svenc_direct(
    const float* __restrict__ sampled_xyz,
    const float* __restrict__ point_xyz,
    const float* __restrict__ values,
    const int*   __restrict__ sampled_idx,
    const int*   __restrict__ point_feats,
    float*       __restrict__ out,
    int P)
{
    int t   = blockIdx.x * blockDim.x + threadIdx.x;
    int pid = t >> 3;
    int sub = t & 7;
    if (pid >= P) return;

    int vi = __builtin_nontemporal_load(sampled_idx + pid);
    float sx = __builtin_nontemporal_load(sampled_xyz + pid * 3 + 0);
    float sy = __builtin_nontemporal_load(sampled_xyz + pid * 3 + 1);
    float sz = __builtin_nontemporal_load(sampled_xyz + pid * 3 + 2);

    float cx = point_xyz[(size_t)vi * 3 + 0];
    float cy = point_xyz[(size_t)vi * 3 + 1];
    float cz = point_xyz[(size_t)vi * 3 + 2];

    float px = (sx - cx) * VOXEL_INV + 0.5f;
    float py = (sy - cy) * VOXEL_INV + 0.5f;
    float pz = (sz - cz) * VOXEL_INV + 0.5f;

    float xs[2] = {1.0f - px, px};
    float ys[2] = {1.0f - py, py};
    float zs[2] = {1.0f - pz, pz};

    int ids[8];
    corner_ids(point_feats, vi, ids);

    vfloat4 acc = {0.0f, 0.0f, 0.0f, 0.0f};
#pragma unroll
    for (int c = 0; c < 8; ++c) {
        float w = xs[(c >> 2) & 1] * ys[(c >> 1) & 1] * zs[c & 1];
        const vfloat4 v = ((const vfloat4*)(values + ((size_t)ids[c] << 5)))[sub];
        acc += w * v;
    }
    __builtin_nontemporal_store(acc, (vfloat4*)(out + ((size_t)pid << 5)) + sub);
}

// ------------------------------------------------------- tier 1: xyz buckets
__global__ __launch_bounds__(256) void k_bucket_xyz(
    const float* __restrict__ sampled_xyz,
    const float* __restrict__ point_xyz,
    const float* __restrict__ values,
    const int*   __restrict__ sampled_idx,
    const int*   __restrict__ point_feats,
    float*       __restrict__ out,
    int*         __restrict__ counts,
    vfloat4*     __restrict__ bucket,   // [H*CAP] {bitcast(p), sx, sy, sz}
    int P)
{
    int p = blockIdx.x * 256 + threadIdx.x;
    if (p >= P) return;

    int vi = __builtin_nontemporal_load(sampled_idx + p);

    // issue the atomic FIRST (independent of xyz) so its latency overlaps
    // the xyz loads
    int pos = atomicAdd(counts + vi, 1);

    float sx = __builtin_nontemporal_load(sampled_xyz + (size_t)p * 3 + 0);
    float sy = __builtin_nontemporal_load(sampled_xyz + (size_t)p * 3 + 1);
    float sz = __builtin_nontemporal_load(sampled_xyz + (size_t)p * 3 + 2);

    if (pos < CAP) {
        vfloat4 e;
        e.x = __int_as_float(p);
        e.y = sx; e.z = sy; e.w = sz;
        // scattered partial-line store: nt = no-allocate hint (the R7 theory)
        __builtin_nontemporal_store(e, bucket + ((size_t)vi << 3) + pos);
    } else {
        // rare (~1e2 points total): compute in-place, fully correct
        compute_point_direct(point_xyz, values, point_feats, out, vi, p, sx, sy, sz);
    }
}

__global__ __launch_bounds__(256) void svenc_voxel_xyz(
    const float* __restrict__ point_xyz,
    const float* __restrict__ values,
    const int*   __restrict__ point_feats,
    const int*   __restrict__ counts,
    const vfloat4* __restrict__ bucket,
    float*       __restrict__ out,
    int H)
{
    int t   = blockIdx.x * 256 + threadIdx.x;
    int g   = t >> 3;       // voxel index (sequential -> streaming voxel tables)
    int sub = t & 7;        // float4 chunk of the 32-float row
    if (g >= H) return;

    int n = __builtin_nontemporal_load(counts + g);   // read-once stream
    if (n == 0) return;
    if (n > CAP) n = CAP;

    float cx = point_xyz[(size_t)g * 3 + 0];
    float cy = point_xyz[(size_t)g * 3 + 1];
    float cz = point_xyz[(size_t)g * 3 + 2];

    int ids[8];
    corner_ids(point_feats, g, ids);

    // 8 corner rows loaded ONCE into registers, reused for all points in voxel
    vfloat4 v[8];
#pragma unroll
    for (int c = 0; c < 8; ++c)
        v[c] = ((const vfloat4*)(values + ((size_t)ids[c] << 5)))[sub];

    for (int i = 0; i < n; ++i) {
        // read-once; nt keeps `values` resident in L2
        vfloat4 e = __builtin_nontemporal_load(bucket + ((size_t)g << 3) + i);
        int p = __float_as_int(e.x);

        float px = (e.y - cx) * VOXEL_INV + 0.5f;
        float py = (e.z - cy) * VOXEL_INV + 0.5f;
        float pz = (e.w - cz) * VOXEL_INV + 0.5f;

        float xs[2] = {1.0f - px, px};
        float ys[2] = {1.0f - py, py};
        float zs[2] = {1.0f - pz, pz};

        vfloat4 acc = {0.0f, 0.0f, 0.0f, 0.0f};
#pragma unroll
        for (int c = 0; c < 8; ++c) {
            float w = xs[(c >> 2) & 1] * ys[(c >> 1) & 1] * zs[c & 1];
            acc += w * v[c];
        }
        __builtin_nontemporal_store(acc, (vfloat4*)(out + ((size_t)p << 5)) + sub);
    }
}

// -------------------------------------------------------- tier 2: id buckets
__global__ __launch_bounds__(256) void k_bucket_id(
    const float* __restrict__ sampled_xyz,
    const float* __restrict__ point_xyz,
    const float* __restrict__ values,
    const int*   __restrict__ sampled_idx,
    const int*   __restrict__ point_feats,
    float*       __restrict__ out,
    int*         __restrict__ counts,
    int*         __restrict__ bucket,   // [H*CAP] point ids
    int P)
{
    int p = blockIdx.x * 256 + threadIdx.x;
    if (p >= P) return;

    int vi = sampled_idx[p];
    int pos = atomicAdd(counts + vi, 1);
    if (pos < CAP) {
        __builtin_nontemporal_store(p, bucket + ((size_t)vi << 3) + pos);
    } else {
        float sx = sampled_xyz[(size_t)p * 3 + 0];
        float sy = sampled_xyz[(size_t)p * 3 + 1];
        float sz = sampled_xyz[(size_t)p * 3 + 2];
        compute_point_direct(point_xyz, values, point_feats, out, vi, p, sx, sy, sz);
    }
}

__global__ __launch_bounds__(256) void svenc_voxel_id(
    const float* __restrict__ sampled_xyz,
    const float* __restrict__ point_xyz,
    const float* __restrict__ values,
    const int*   __restrict__ point_feats,
    const int*   __restrict__ counts,
    const int*   __restrict__ bucket,
    float*       __restrict__ out,
    int H)
{
    int t   = blockIdx.x * 256 + threadIdx.x;
    int g   = t >> 3;
    int sub = t & 7;
    if (g >= H) return;

    int n = counts[g];
    if (n == 0) return;
    if (n > CAP) n = CAP;

    float cx = point_xyz[(size_t)g * 3 + 0];
    float cy = point_xyz[(size_t)g * 3 + 1];
    float cz = point_xyz[(size_t)g * 3 + 2];

    int ids[8];
    corner_ids(point_feats, g, ids);

    vfloat4 v[8];
#pragma unroll
    for (int c = 0; c < 8; ++c)
        v[c] = ((const vfloat4*)(values + ((size_t)ids[c] << 5)))[sub];

    for (int i = 0; i < n; ++i) {
        int p = bucket[((size_t)g << 3) + i];

        float sx = sampled_xyz[(size_t)p * 3 + 0];
        float sy = sampled_xyz[(size_t)p * 3 + 1];
        float sz = sampled_xyz[(size_t)p * 3 + 2];

        float px = (sx - cx) * VOXEL_INV + 0.5f;
        float py = (sy - cy) * VOXEL_INV + 0.5f;
        float pz = (sz - cz) * VOXEL_INV + 0.5f;

        float xs[2] = {1.0f - px, px};
        float ys[2] = {1.0f - py, py};
        float zs[2] = {1.0f - pz, pz};

        vfloat4 acc = {0.0f, 0.0f, 0.0f, 0.0f};
#pragma unroll
        for (int c = 0; c < 8; ++c) {
            float w = xs[(c >> 2) & 1] * ys[(c >> 1) & 1] * zs[c & 1];
            acc += w * v[c];
        }
        __builtin_nontemporal_store(acc, (vfloat4*)(out + ((size_t)p << 5)) + sub);
    }
}

// ---------------------------------------------------------------- launcher
extern "C" void kernel_launch(void* const* d_in, const int* in_sizes, int n_in,
                              void* d_out, int out_size, void* d_ws, size_t ws_size,
                              hipStream_t stream) {
    const float* sampled_xyz = (const float*)d_in[0];
    const float* point_xyz   = (const float*)d_in[1];
    const float* values      = (const float*)d_in[2];
    const int*   sampled_idx = (const int*)d_in[3];
    const int*   point_feats = (const int*)d_in[4];
    float* out = (float*)d_out;

    int P = in_sizes[3];   // element count of sampled_idx == number of points

    // H: handle both in_sizes conventions (total elements vs first-dim).
    int H;
    if (in_sizes[0] == 3 * P)       H = in_sizes[4] / 8;
    else                            H = in_sizes[4];

    size_t bucketB_xyz = (size_t)H * CAP * 16;   // vfloat4 per slot
    size_t need_xyz    = bucketB_xyz + (size_t)H * 4;
    size_t bucketB_id  = (size_t)H * CAP * 4;
    size_t need_id     = bucketB_id + (size_t)H * 4;

    int gp = (P + 255) / 256;                    // one thread per point
    long tt = (long)H * 8;
    int gm = (int)((tt + 255) / 256);            // 8 lanes per voxel

    if (d_ws != nullptr && ws_size >= need_xyz && H > 0) {
        vfloat4* bucket = (vfloat4*)d_ws;
        int* counts = (int*)((char*)d_ws + bucketB_xyz);
        hipMemsetAsync(counts, 0, (size_t)H * 4, stream);
        k_bucket_xyz<<<gp, 256, 0, stream>>>(
            sampled_xyz, point_xyz, values, sampled_idx, point_feats,
            out, counts, bucket, P);
        svenc_voxel_xyz<<<gm, 256, 0, stream>>>(
            point_xyz, values, point_feats, counts, bucket, out, H);
    } else if (d_ws != nullptr && ws_size >= need_id && H > 0) {
        int* bucket = (int*)d_ws;
        int* counts = (int*)((char*)d_ws + bucketB_id);
        hipMemsetAsync(counts, 0, (size_t)H * 4, stream);
        k_bucket_id<<<gp, 256, 0, stream>>>(
            sampled_xyz, point_xyz, values, sampled_idx, point_feats,
            out, counts, bucket, P);
        svenc_voxel_id<<<gm, 256, 0, stream>>>(
            sampled_xyz, point_xyz, values, point_feats, counts, bucket, out, H);
    } else {
        long total_threads = (long)P * 8;
        int grid = (int)((total_threads + 255) / 256);
        svenc_direct<<<grid, 256, 0, stream>>>(
            sampled_xyz, point_xyz, values, sampled_idx, point_feats, out, P);
    }
}